// Round 1
// 324.584 us; speedup vs baseline: 1.0992x; 1.0992x over previous
//
#include <hip/hip_runtime.h>
#include <math.h>

constexpr int N = 100000;
constexpr int E = 1600000;
constexpr int C = 128;
constexpr int NPB   = 256;                       // nodes per bucket (pow2 -> shifts)
constexpr int NBUCK = (N + NPB - 1) / NPB;       // 391 buckets
constexpr int CAP   = 9472;                      // staging cap/bucket (mean 8192, +14 sigma)

__device__ inline unsigned f2bf(float f) {   // fp32 -> bf16 bits, RNE
    unsigned u = __float_as_uint(f);
    return (u + 0x7fffu + ((u >> 16) & 1u)) >> 16;
}
__device__ inline unsigned pack2(float lo, float hi) {
    return f2bf(lo) | (f2bf(hi) << 16);
}
__device__ inline float bf_lo(unsigned m) { return __uint_as_float(m << 16); }
__device__ inline float bf_hi(unsigned m) { return __uint_as_float(m & 0xffff0000u); }

// ------------------------------------------------------------- bin pass ----
// One pass over the edge list; NO per-node global atomics. Entry packed to
// 4 B: (dst_local<<17)|src (9+17 bits). NPB=256 so bucket id = u>>8 (shift,
// no magic-mul divide). Per 2048-edge tile: LDS bucket counts -> one global
// atomic per non-empty bucket -> dense appends.
__global__ __launch_bounds__(256) void k_bin(const int* __restrict__ ei,
                                             int* __restrict__ gcount,
                                             unsigned* __restrict__ staging) {
    __shared__ int cnt[NBUCK];
    __shared__ int wbase[NBUCK];
    const int t = threadIdx.x;
    const long tile = (long)blockIdx.x * 2048;
    for (int i = t; i < NBUCK; i += 256) cnt[i] = 0;
    __syncthreads();
    int b0[8], b1[8], lo0[8], lo1[8];
    unsigned p0[8], p1[8];
    bool val[8];
#pragma unroll
    for (int j = 0; j < 8; ++j) {
        long e = tile + j * 256 + t;
        val[j] = e < E;
        if (val[j]) {
            int u = __builtin_nontemporal_load(ei + e);
            int v = __builtin_nontemporal_load(ei + E + e);
            b0[j] = u >> 8;
            b1[j] = v >> 8;
            p0[j] = ((unsigned)(u & 255) << 17) | (unsigned)v;
            p1[j] = ((unsigned)(v & 255) << 17) | (unsigned)u;
            lo0[j] = atomicAdd(&cnt[b0[j]], 1);
            lo1[j] = atomicAdd(&cnt[b1[j]], 1);
        }
    }
    __syncthreads();
    for (int i = t; i < NBUCK; i += 256) wbase[i] = atomicAdd(&gcount[i], cnt[i]);
    __syncthreads();
#pragma unroll
    for (int j = 0; j < 8; ++j) {
        if (val[j]) {
            staging[(size_t)b0[j] * CAP + wbase[b0[j]] + lo0[j]] = p0[j];
            staging[(size_t)b1[j] * CAP + wbase[b1[j]] + lo1[j]] = p1[j];
        }
    }
}

// -------------------------------------------------- per-bucket CSR build ---
// One 512-thread WG per bucket (391 blocks -> 6x the block parallelism of
// the old 64-bucket layout, which capped at 64 CUs). Pass 1: LDS histogram
// -> deg/dinv/rowptr. In-LDS exclusive scan (256 slots, 1/thread). Pass 2:
// LDS cursor atomics -> adj slice. Zero global atomics.
__global__ __launch_bounds__(512) void k_csr(const unsigned* __restrict__ staging,
                                             const int* __restrict__ gcount,
                                             int* __restrict__ deg,
                                             float* __restrict__ dinv,
                                             int* __restrict__ rowptr,
                                             int* __restrict__ adj) {
    __shared__ int hist[NPB + 1];
    __shared__ int wpart[8];
    __shared__ int wsum[8];
    __shared__ int sh_base;
    const int g = blockIdx.x;
    const int t = threadIdx.x;
    const int lane = t & 63, wid = t >> 6;
    const int cnt = gcount[g];
    // block-parallel prefix: base = sum gcount[0..g)  (g <= 390 < 512)
    int s = (t < g) ? gcount[t] : 0;
#pragma unroll
    for (int off = 32; off; off >>= 1) s += __shfl_down(s, off);
    if (lane == 0) wsum[wid] = s;
    for (int i = t; i <= NPB; i += 512) hist[i] = 0;
    __syncthreads();
    if (t == 0) {
        int r = 0;
#pragma unroll
        for (int w = 0; w < 8; ++w) r += wsum[w];
        sh_base = r;
    }
    // pass 1: histogram of local dest ids
    const unsigned* base = staging + (size_t)g * CAP;
    for (int i = t; i < cnt; i += 512) atomicAdd(&hist[base[i] >> 17], 1);
    __syncthreads();
    // exclusive scan of hist[0..256): 1 slot/thread, 4 active waves
    const int a = (t < NPB) ? hist[t] : 0;
    int v = a;
#pragma unroll
    for (int off = 1; off < 64; off <<= 1) {
        int n = __shfl_up(v, off);
        if (lane >= off) v += n;
    }
    if (lane == 63 && wid < NPB / 64) wpart[wid] = v;
    __syncthreads();
    if (t == 0) {
        int r = 0;
#pragma unroll
        for (int w = 0; w < NPB / 64; ++w) { int x = wpart[w]; wpart[w] = r; r += x; }
    }
    __syncthreads();
    if (t < NPB) hist[t] = v - a + wpart[wid];
    if (t == 0) hist[NPB] = cnt;
    __syncthreads();
    // dense deg/dinv/rowptr writes for this bucket's nodes
    const int nbase = g * NPB;
    const int nlocal = min(NPB, N - nbase);
    const int bbase = sh_base;
    if (t < nlocal) {
        const int st = hist[t], en = hist[t + 1];
        const int d = en - st;
        deg[nbase + t] = d;
        dinv[nbase + t] = rsqrtf((float)d + 1.0f);
        rowptr[nbase + t] = bbase + st;
    }
    __syncthreads();
    // pass 2: fill adj via LDS cursors
    int* aslice = adj + bbase;
    for (int i = t; i < cnt; i += 512) {
        const unsigned e = base[i];
        const int pos = atomicAdd(&hist[e >> 17], 1);
        aslice[pos] = (int)(e & 0x1ffffu);
    }
}

// ------------------------------------------------------------------ GEMM ---
// z16 = bf16(dinv[row] * (x @ W)). Pre-scaling by dinv[src] here removes the
// per-edge dv gather + weight multiply from k_gather entirely:
//   out[u] = du * (sum_{v in adj(u)} z[v] + z[u]) + b
// Error model identical to unscaled (du*dv*xw*2^-9 either way).
__global__ __launch_bounds__(256) void k_gemm(const float* __restrict__ x,
                                              const float* __restrict__ W,
                                              const float* __restrict__ dinv,
                                              unsigned* __restrict__ z16) {
    __shared__ float Ws[32][128];
    __shared__ float xs[64][33];

    const int t   = threadIdx.x;
    const int r0  = (t & 15) * 4;
    const int c0  = (t >> 4) * 8;
    const int bid = blockIdx.x;

    float acc[4][8];
#pragma unroll
    for (int i = 0; i < 4; ++i)
#pragma unroll
        for (int j = 0; j < 8; ++j) acc[i][j] = 0.0f;

    const int lrow = t >> 2;
    const int lk   = (t & 3) * 8;
    const long grow = (long)bid * 64 + lrow;
    const bool rvalid = grow < N;

    for (int k0 = 0; k0 < C; k0 += 32) {
        const float4* Wg = (const float4*)(W + (size_t)k0 * C);
        float4* Wsv = (float4*)(&Ws[0][0]);
#pragma unroll
        for (int j = 0; j < 4; ++j) Wsv[t + 256 * j] = Wg[t + 256 * j];
        float4 a0 = {0, 0, 0, 0}, a1 = {0, 0, 0, 0};
        if (rvalid) {
            a0 = *(const float4*)(x + grow * C + k0 + lk);
            a1 = *(const float4*)(x + grow * C + k0 + lk + 4);
        }
        xs[lrow][lk + 0] = a0.x; xs[lrow][lk + 1] = a0.y;
        xs[lrow][lk + 2] = a0.z; xs[lrow][lk + 3] = a0.w;
        xs[lrow][lk + 4] = a1.x; xs[lrow][lk + 5] = a1.y;
        xs[lrow][lk + 6] = a1.z; xs[lrow][lk + 7] = a1.w;
        __syncthreads();

#pragma unroll 8
        for (int k = 0; k < 32; ++k) {
            float4 w0 = *(const float4*)&Ws[k][c0];
            float4 w1 = *(const float4*)&Ws[k][c0 + 4];
            float xv[4];
#pragma unroll
            for (int i = 0; i < 4; ++i) xv[i] = xs[r0 + i][k];
#pragma unroll
            for (int i = 0; i < 4; ++i) {
                acc[i][0] = fmaf(xv[i], w0.x, acc[i][0]);
                acc[i][1] = fmaf(xv[i], w0.y, acc[i][1]);
                acc[i][2] = fmaf(xv[i], w0.z, acc[i][2]);
                acc[i][3] = fmaf(xv[i], w0.w, acc[i][3]);
                acc[i][4] = fmaf(xv[i], w1.x, acc[i][4]);
                acc[i][5] = fmaf(xv[i], w1.y, acc[i][5]);
                acc[i][6] = fmaf(xv[i], w1.z, acc[i][6]);
                acc[i][7] = fmaf(xv[i], w1.w, acc[i][7]);
            }
        }
        __syncthreads();
    }

#pragma unroll
    for (int i = 0; i < 4; ++i) {
        long r = (long)bid * 64 + r0 + i;
        if (r >= N) break;
        const float dv = dinv[r];
        uint4 pk = {pack2(dv * acc[i][0], dv * acc[i][1]), pack2(dv * acc[i][2], dv * acc[i][3]),
                    pack2(dv * acc[i][4], dv * acc[i][5]), pack2(dv * acc[i][6], dv * acc[i][7])};
        *(uint4*)(z16 + r * (C / 2) + (c0 >> 1)) = pk;
    }
}

// ---------------------------------------------------------------- gather ---
// One wave per node; lane owns channels 2*lane, 2*lane+1.
//   out[u] = du * (sum z[v] + z[u]) + b       (z already dinv-scaled)
// Scalarized inner loop: readlane puts the neighbor id in an SGPR, so the
// z16 row base is scalar (SALU) and each edge costs 1 VMEM + ~5 VALU
// (readlane + 2 unpacks + 2 adds) with 8 loads in flight.
__global__ __launch_bounds__(256) void k_gather(const int* __restrict__ rowptr,
                                                const int* __restrict__ deg,
                                                const float* __restrict__ dinv,
                                                const int* __restrict__ adj,
                                                const unsigned* __restrict__ z16,
                                                const float* __restrict__ b,
                                                float* __restrict__ out) {
    const int u = blockIdx.x * 4 + (threadIdx.x >> 6);
    if (u >= N) return;
    const int lane = threadIdx.x & 63;
    const int d  = __builtin_amdgcn_readfirstlane(deg[u]);
    const int st = __builtin_amdgcn_readfirstlane(rowptr[u]);
    const float du = dinv[u];
    // self-loop: z[u] (final *du gives du^2 * xw[u])
    const unsigned ms = z16[((unsigned)u << 6) + lane];
    float ax0 = bf_lo(ms), ay0 = bf_hi(ms);
    float ax1 = 0.f, ay1 = 0.f;

    for (int j0 = 0; j0 < d; j0 += 64) {
        int v = 0;
        if (j0 + lane < d) v = adj[st + j0 + lane];
        const int cntc = min(64, d - j0);
        int jj = 0;
        for (; jj + 8 <= cntc; jj += 8) {
            const int v0 = __builtin_amdgcn_readlane(v, jj + 0);
            const int v1 = __builtin_amdgcn_readlane(v, jj + 1);
            const int v2 = __builtin_amdgcn_readlane(v, jj + 2);
            const int v3 = __builtin_amdgcn_readlane(v, jj + 3);
            const int v4 = __builtin_amdgcn_readlane(v, jj + 4);
            const int v5 = __builtin_amdgcn_readlane(v, jj + 5);
            const int v6 = __builtin_amdgcn_readlane(v, jj + 6);
            const int v7 = __builtin_amdgcn_readlane(v, jj + 7);
            const unsigned m0 = (z16 + (((size_t)(unsigned)v0) << 6))[lane];
            const unsigned m1 = (z16 + (((size_t)(unsigned)v1) << 6))[lane];
            const unsigned m2 = (z16 + (((size_t)(unsigned)v2) << 6))[lane];
            const unsigned m3 = (z16 + (((size_t)(unsigned)v3) << 6))[lane];
            const unsigned m4 = (z16 + (((size_t)(unsigned)v4) << 6))[lane];
            const unsigned m5 = (z16 + (((size_t)(unsigned)v5) << 6))[lane];
            const unsigned m6 = (z16 + (((size_t)(unsigned)v6) << 6))[lane];
            const unsigned m7 = (z16 + (((size_t)(unsigned)v7) << 6))[lane];
            ax0 += bf_lo(m0); ay0 += bf_hi(m0);
            ax1 += bf_lo(m1); ay1 += bf_hi(m1);
            ax0 += bf_lo(m2); ay0 += bf_hi(m2);
            ax1 += bf_lo(m3); ay1 += bf_hi(m3);
            ax0 += bf_lo(m4); ay0 += bf_hi(m4);
            ax1 += bf_lo(m5); ay1 += bf_hi(m5);
            ax0 += bf_lo(m6); ay0 += bf_hi(m6);
            ax1 += bf_lo(m7); ay1 += bf_hi(m7);
        }
        for (; jj < cntc; ++jj) {
            const int vv = __builtin_amdgcn_readlane(v, jj);
            const unsigned m = (z16 + (((size_t)(unsigned)vv) << 6))[lane];
            ax0 += bf_lo(m); ay0 += bf_hi(m);
        }
    }
    const float2 bb = *(const float2*)(b + 2 * lane);
    const float ax = ax0 + ax1, ay = ay0 + ay1;
    float2 o = {fmaf(du, ax, bb.x), fmaf(du, ay, bb.y)};
    *(float2*)(out + (size_t)u * C + 2 * lane) = o;
}

// ---------------------------------------------------------------- launch ---
extern "C" void kernel_launch(void* const* d_in, const int* in_sizes, int n_in,
                              void* d_out, int out_size, void* d_ws, size_t ws_size,
                              hipStream_t stream) {
    const float* x  = (const float*)d_in[0];
    const float* W  = (const float*)d_in[1];
    const float* b  = (const float*)d_in[2];
    const int*   ei = (const int*)d_in[3];
    float* out = (float*)d_out;

    // workspace: z16 [N*64 u32] | deg [N] | dinv [N] | rowptr [N+4] |
    //            gcount [512] | staging [NBUCK*CAP u32] | adj [2E]
    char* p = (char*)d_ws;
    unsigned* z16 = (unsigned*)p;   p += (size_t)N * (C / 2) * sizeof(unsigned);
    int* deg = (int*)p;             p += (size_t)N * sizeof(int);
    float* dinv = (float*)p;        p += (size_t)N * sizeof(float);
    int* rowptr = (int*)p;          p += (size_t)(N + 4) * sizeof(int);
    int* gcount = (int*)p;          p += 512 * sizeof(int);
    unsigned* staging = (unsigned*)p; p += (size_t)NBUCK * CAP * sizeof(unsigned);
    int* adj = (int*)p;

    hipMemsetAsync(gcount, 0, 512 * sizeof(int), stream);
    k_bin<<<(E + 2047) / 2048, 256, 0, stream>>>(ei, gcount, staging);
    k_csr<<<NBUCK, 512, 0, stream>>>(staging, gcount, deg, dinv, rowptr, adj);
    k_gemm<<<(N + 63) / 64, 256, 0, stream>>>(x, W, dinv, z16);
    k_gather<<<(N + 3) / 4, 256, 0, stream>>>(rowptr, deg, dinv, adj, z16, b, out);
}